// Round 4
// baseline (321.009 us; speedup 1.0000x reference)
//
#include <hip/hip_runtime.h>

#define DEVFN __device__ __forceinline__

// NaN-propagating relu (fmaxf(NaN,0)==0 would mask upstream failures).
DEVFN float relu(float x) { return x < 0.f ? 0.f : x; }

// ---------------------------------------------------------------------------
// KA: fused pre-work, roles interleaved bx%5: 0..3 src (4 rows each), 4 nbr.
//  src role : src = features@in_w+in_b + relu(pe)@pe_w2+pe_b2 ; qs/ks/vs
//  nbr role : neighbor top-16 (manhattan<=4, stable); nbr-block 0 zeros BN.
// 4-row blocks + __launch_bounds__(256,8): ~8 blocks/CU (~32 waves/CU) vs 4
// before — rounds 0-3 showed VALUBusy ~50%/occ 30% with all waves
// barrier-locked; independent small blocks overlap each other's stalls.
// Inner loops are round-0 form: (col, K)-mapping, zero weight redundancy,
// no unroll pragmas (round-2: full-unroll hoist spills; round-3: unroll 1
// serializes loads).
// ---------------------------------------------------------------------------
__global__ __launch_bounds__(256, 8) void ka_pre_cst(
    const float* __restrict__ features, const int* __restrict__ coords,
    const float* __restrict__ pe_w1, const float* __restrict__ pe_b1,
    const float* __restrict__ pe_w2, const float* __restrict__ pe_b2,
    const float* __restrict__ in_w, const float* __restrict__ in_b,
    const float* __restrict__ q_w, const float* __restrict__ k_w,
    const float* __restrict__ v_w,
    float* __restrict__ src,
    float* __restrict__ qs, float* __restrict__ ks, float* __restrict__ vs,
    int* __restrict__ nbr, float* __restrict__ bnAcc, int N)
{
    // src-role LDS (4 rows)
    __shared__ float sF[256];   // 4 x 64 features
    __shared__ float sH[256];   // 4 x 64 pe-hidden
    __shared__ __align__(16) float S[512];    // 4 x 128 src
    __shared__ int   sC[12];
    // nbr-role LDS
    __shared__ int cnt[16];
    __shared__ int lst[16 * 64];
    __shared__ int outL[256];

    const int tid = threadIdx.x;
    const int bx = blockIdx.x;
    const int role_nbr = (bx % 5) == 4;

    if (role_nbr) {
        // ---------------- nbr role: neighbor search -----------------------
        const int nb = bx / 5;
        const int q0 = nb * 16;
        if (nb == 0 && tid < 128) bnAcc[tid] = 0.f;
        if (tid < 16) cnt[tid] = 0;
        outL[tid] = -1;
        __syncthreads();
        int qx[16], qy[16], qz[16];
#pragma unroll
        for (int q = 0; q < 16; ++q) {
            qx[q] = coords[(q0 + q) * 3 + 0];
            qy[q] = coords[(q0 + q) * 3 + 1];
            qz[q] = coords[(q0 + q) * 3 + 2];
        }
        for (int cd = tid; cd < N; cd += 256) {
            int cx = coords[cd * 3 + 0];
            int cy = coords[cd * 3 + 1];
            int cz = coords[cd * 3 + 2];
#pragma unroll
            for (int q = 0; q < 16; ++q) {
                int dx = cx - qx[q]; dx = dx < 0 ? -dx : dx;
                int dy = cy - qy[q]; dy = dy < 0 ? -dy : dy;
                int dz = cz - qz[q]; dz = dz < 0 ? -dz : dz;
                int d = dx + dy + dz;
                if (d <= 4) {
                    int s = atomicAdd(&cnt[q], 1);
                    if (s < 64) lst[q * 64 + s] = (d << 13) | cd;
                }
            }
        }
        __syncthreads();
        {
            const int q = tid >> 4, t = tid & 15;
            int n = cnt[q]; if (n > 64) n = 64;
            for (int e = t; e < n; e += 16) {
                int key = lst[q * 64 + e];
                int rank = 0;
                for (int j = 0; j < n; ++j) rank += (lst[q * 64 + j] < key) ? 1 : 0;
                if (rank < 16) outL[q * 16 + rank] = key & 8191;
            }
        }
        __syncthreads();
        {
            const int q = tid >> 4, t = tid & 15;
            nbr[(q0 + q) * 16 + t] = outL[q * 16 + t];
        }
        return;
    }

    // ---------------- src role: 4 rows; src + q/k/v projections -----------
    const int sidx = (bx / 5) * 4 + (bx % 5);   // 0..2047
    const int r0 = sidx * 4;
    if (tid < 12) sC[tid] = coords[r0 * 3 + tid];
    if (tid < 256) sF[tid] = features[r0 * 64 + tid];
    __syncthreads();
    if (tid < 256) {
        int r = tid >> 6, t = tid & 63;
        float v0 = sC[r * 3 + 0] * (1.f / 95.f);
        float v1 = sC[r * 3 + 1] * (1.f / 95.f);
        float v2 = sC[r * 3 + 2] * (1.f / 95.f);
        float h = v0 * pe_w1[t] + v1 * pe_w1[64 + t] + v2 * pe_w1[128 + t] + pe_b1[t];
        sH[tid] = relu(h);
    }
    __syncthreads();
    const int c = tid & 127, rh = tid >> 7;   // rows rh*2 + r, r<2
    {
        float acc[2];
        const float base = in_b[c] + pe_b2[c];
#pragma unroll
        for (int r = 0; r < 2; ++r) acc[r] = base;
        for (int j = 0; j < 64; ++j) {
            float w1 = in_w[j * 128 + c];
            float w2 = pe_w2[j * 128 + c];
#pragma unroll
            for (int r = 0; r < 2; ++r) {
                int rr = rh * 2 + r;
                acc[r] += sF[rr * 64 + j] * w1 + sH[rr * 64 + j] * w2;
            }
        }
#pragma unroll
        for (int r = 0; r < 2; ++r) {
            src[(r0 + rh * 2 + r) * 128 + c] = acc[r];
            S[(rh * 2 + r) * 128 + c] = acc[r];
        }
    }
    __syncthreads();
    // q/k/v in one pass: 12 concurrent weight streams for latency hiding
    {
        float aq[2], ak[2], av[2];
#pragma unroll
        for (int r = 0; r < 2; ++r) { aq[r] = 0.f; ak[r] = 0.f; av[r] = 0.f; }
        for (int k4 = 0; k4 < 32; ++k4) {
            float wq0 = q_w[(k4 * 4 + 0) * 128 + c];
            float wq1 = q_w[(k4 * 4 + 1) * 128 + c];
            float wq2 = q_w[(k4 * 4 + 2) * 128 + c];
            float wq3 = q_w[(k4 * 4 + 3) * 128 + c];
            float wk0 = k_w[(k4 * 4 + 0) * 128 + c];
            float wk1 = k_w[(k4 * 4 + 1) * 128 + c];
            float wk2 = k_w[(k4 * 4 + 2) * 128 + c];
            float wk3 = k_w[(k4 * 4 + 3) * 128 + c];
            float wv0 = v_w[(k4 * 4 + 0) * 128 + c];
            float wv1 = v_w[(k4 * 4 + 1) * 128 + c];
            float wv2 = v_w[(k4 * 4 + 2) * 128 + c];
            float wv3 = v_w[(k4 * 4 + 3) * 128 + c];
#pragma unroll
            for (int r = 0; r < 2; ++r) {
                float4 s = *(const float4*)(&S[(rh * 2 + r) * 128 + k4 * 4]);
                aq[r] += s.x * wq0 + s.y * wq1 + s.z * wq2 + s.w * wq3;
                ak[r] += s.x * wk0 + s.y * wk1 + s.z * wk2 + s.w * wk3;
                av[r] += s.x * wv0 + s.y * wv1 + s.z * wv2 + s.w * wv3;
            }
        }
#pragma unroll
        for (int r = 0; r < 2; ++r) {
            qs[(r0 + rh * 2 + r) * 128 + c] = aq[r];
            ks[(r0 + rh * 2 + r) * 128 + c] = ak[r];
            vs[(r0 + rh * 2 + r) * 128 + c] = av[r];
        }
    }
}

// ---------------------------------------------------------------------------
// K4: attention + o-proj + LN1 + FFN + LN2 + fusion + BN partials.
// 4 rows/block, 2048 blocks, ~8 blocks/CU. Round-0 inner mappings
// ((col,K)-split, zero weight redundancy, compiler-scheduled loads).
// ---------------------------------------------------------------------------
DEVFN void ln_rows4(float* Cb, const float* __restrict__ g,
                    const float* __restrict__ b, int tid)
{
    // row = wave (tid>>6), lane handles cols l and l+64
    const int r = tid >> 6, l = tid & 63;
    float x0 = Cb[r * 128 + l];
    float x1 = Cb[r * 128 + l + 64];
    float s = x0 + x1, s2 = x0 * x0 + x1 * x1;
#pragma unroll
    for (int o = 1; o < 64; o <<= 1) { s += __shfl_xor(s, o); s2 += __shfl_xor(s2, o); }
    float mu = s * (1.f / 128.f);
    float var = s2 * (1.f / 128.f) - mu * mu;
    float rstd = rsqrtf(var + 1e-5f);
    Cb[r * 128 + l]      = (x0 - mu) * rstd * g[l]      + b[l];
    Cb[r * 128 + l + 64] = (x1 - mu) * rstd * g[l + 64] + b[l + 64];
}

__global__ __launch_bounds__(256, 8) void k4_main_cst(
    const float* __restrict__ features, const float* __restrict__ src,
    const float* __restrict__ qs, const float* __restrict__ ks, const float* __restrict__ vs,
    const int* __restrict__ nbr,
    const float* __restrict__ q_b, const float* __restrict__ k_b,
    const float* __restrict__ v_b,
    const float* __restrict__ o_w, const float* __restrict__ o_b,
    const float* __restrict__ n1_g, const float* __restrict__ n1_b,
    const float* __restrict__ l1_w, const float* __restrict__ l1_b,
    const float* __restrict__ l2_w, const float* __restrict__ l2_b,
    const float* __restrict__ n3_g, const float* __restrict__ n3_b,
    const float* __restrict__ fu_w, const float* __restrict__ fu_b,
    float* __restrict__ fused, float* __restrict__ bnSum, float* __restrict__ bnSq)
{
    __shared__ __align__(16) float A[512];    // src tile / P4 partial kh=1
    __shared__ __align__(16) float Bt[512];   // head_out
    __shared__ __align__(16) float C[512];    // running activation
    __shared__ __align__(16) float Q[512];    // q rows (bias applied)
    __shared__ __align__(16) float H[1024];   // P2 partials / ffn hidden / bn staging
    __shared__ __align__(16) float SC[256];   // attention scores
    __shared__ __align__(16) float F[256];    // features tile
    __shared__ __align__(16) float bK[128], bV[128];
    __shared__ int idxL[64];
    const int tid = threadIdx.x;
    const int r0 = blockIdx.x * 4;

    for (int i = tid; i < 512; i += 256) A[i] = src[r0 * 128 + i];
    if (tid < 256) F[tid] = features[r0 * 64 + tid];
    if (tid < 64) idxL[tid] = nbr[r0 * 16 + tid];
    if (tid < 128) { bK[tid] = k_b[tid]; bV[tid] = v_b[tid]; }
    __syncthreads();
    if (tid < 128) {   // Q gather + bias: thread = (row=tid>>5, colgroup=tid&31)
        int r = tid >> 5, cg = tid & 31;
        int i0 = idxL[r * 16];
        float4 qv = make_float4(0.f, 0.f, 0.f, 0.f);
        if (i0 >= 0) qv = *(const float4*)(qs + i0 * 128 + cg * 4);
        float4 qb = *(const float4*)(q_b + cg * 4);
        qv.x += qb.x; qv.y += qb.y; qv.z += qb.z; qv.w += qb.w;
        *(float4*)(&Q[r * 128 + cg * 4]) = qv;
    }
    __syncthreads();

    // ---- phase 1a: scores. thread = (row ar, head ah, j = ag) ------------
    const int ar = tid >> 6, ah = (tid >> 4) & 3, ag = tid & 15;
    {
        const int j = ag;
        const int j4 = j >> 2, ch = j & 3;
        const int id = idxL[ar * 16 + ah * 4 + j4];
        float s = 0.f;
#pragma unroll
        for (int c4 = 0; c4 < 8; ++c4) {
            float4 qv = *(const float4*)(&Q[ar * 128 + ah * 32 + c4 * 4]);
            float4 kb = *(const float4*)(&bK[ch * 32 + c4 * 4]);
            float4 kv = make_float4(0.f, 0.f, 0.f, 0.f);
            if (id >= 0) kv = *(const float4*)(ks + id * 128 + ch * 32 + c4 * 4);
            s += qv.x * (kv.x + kb.x) + qv.y * (kv.y + kb.y)
               + qv.z * (kv.z + kb.z) + qv.w * (kv.w + kb.w);
        }
        SC[ar * 64 + ah * 16 + j] = s * 0.08838834764831845f;  // 1/sqrt(128)
    }
    __syncthreads();

    // ---- phase 1b: softmax (redundant per 16-thread group) + P@V ---------
    {
        float p[16];
        float mx = -3.4e38f;
#pragma unroll
        for (int j = 0; j < 16; ++j) { p[j] = SC[ar * 64 + ah * 16 + j]; mx = fmaxf(mx, p[j]); }
        float sum = 0.f;
#pragma unroll
        for (int j = 0; j < 16; ++j) { p[j] = __expf(p[j] - mx); sum += p[j]; }
        float inv = 1.f / sum;
        // each thread owns 2 cols of its head: ah*32 + ag*2
        float2 acc = make_float2(0.f, 0.f);
        const int co = ah * 32 + ag * 2;
        float2 vb = *(const float2*)(&bV[co]);
#pragma unroll
        for (int j = 0; j < 16; ++j) {
            int j4 = j >> 2;
            int id = idxL[ar * 16 + ah * 4 + j4];
            // NOTE: neighbor slot within 4-group is j&3 (matches round-0 ch)
            float2 vv = make_float2(0.f, 0.f);
            if (id >= 0) vv = *(const float2*)(vs + id * 128 + co);
            float w = p[j] * inv;
            acc.x += w * (vv.x + vb.x);
            acc.y += w * (vv.y + vb.y);
        }
        *(float2*)(&Bt[ar * 128 + co]) = acc;
    }
    __syncthreads();

    // ---- phase 2: out = head_out @ o_w (K-split); C = A + out + o_b ------
    {
        const int c = tid & 127, kh = tid >> 7;
        float acc[4];
#pragma unroll
        for (int r = 0; r < 4; ++r) acc[r] = 0.f;
        const float* wp = o_w + kh * 64 * 128 + c;
        for (int k4 = 0; k4 < 16; ++k4) {
            float w0 = wp[(k4 * 4 + 0) * 128];
            float w1 = wp[(k4 * 4 + 1) * 128];
            float w2 = wp[(k4 * 4 + 2) * 128];
            float w3 = wp[(k4 * 4 + 3) * 128];
#pragma unroll
            for (int r = 0; r < 4; ++r) {
                float4 t = *(const float4*)(&Bt[r * 128 + kh * 64 + k4 * 4]);
                acc[r] += t.x * w0 + t.y * w1 + t.z * w2 + t.w * w3;
            }
        }
#pragma unroll
        for (int r = 0; r < 4; ++r) H[kh * 512 + r * 128 + c] = acc[r];
    }
    __syncthreads();
    for (int i = tid; i < 512; i += 256) {
        int cc = i & 127;
        C[i] = A[i] + o_b[cc] + H[i] + H[512 + i];
    }
    __syncthreads();
    ln_rows4(C, n1_g, n1_b, tid);   // C = tgt
    __syncthreads();

    // ---- phase 3: H = relu(C @ l1_w + l1_b)  [4 x 256] -------------------
    {
        const int f = tid;
        float acc[4];
#pragma unroll
        for (int r = 0; r < 4; ++r) acc[r] = 0.f;
        for (int k4 = 0; k4 < 32; ++k4) {
            float w0 = l1_w[(k4 * 4 + 0) * 256 + f];
            float w1 = l1_w[(k4 * 4 + 1) * 256 + f];
            float w2 = l1_w[(k4 * 4 + 2) * 256 + f];
            float w3 = l1_w[(k4 * 4 + 3) * 256 + f];
#pragma unroll
            for (int r = 0; r < 4; ++r) {
                float4 t = *(const float4*)(&C[r * 128 + k4 * 4]);
                acc[r] += t.x * w0 + t.y * w1 + t.z * w2 + t.w * w3;
            }
        }
        const float bb = l1_b[f];
#pragma unroll
        for (int r = 0; r < 4; ++r) H[r * 256 + f] = relu(acc[r] + bb);
    }
    __syncthreads();

    // ---- phase 4: t2 = H @ l2_w (K-split, partial in A); C += t2 ---------
    {
        const int c = tid & 127, kh = tid >> 7;
        float acc[4];
#pragma unroll
        for (int r = 0; r < 4; ++r) acc[r] = 0.f;
        const float* wp = l2_w + kh * 128 * 128 + c;
        for (int k4 = 0; k4 < 32; ++k4) {
            float w0 = wp[(k4 * 4 + 0) * 128];
            float w1 = wp[(k4 * 4 + 1) * 128];
            float w2 = wp[(k4 * 4 + 2) * 128];
            float w3 = wp[(k4 * 4 + 3) * 128];
#pragma unroll
            for (int r = 0; r < 4; ++r) {
                float4 t = *(const float4*)(&H[r * 256 + kh * 128 + k4 * 4]);
                acc[r] += t.x * w0 + t.y * w1 + t.z * w2 + t.w * w3;
            }
        }
        if (kh) {
#pragma unroll
            for (int r = 0; r < 4; ++r) A[r * 128 + c] = acc[r];
        }
        __syncthreads();
        if (kh == 0) {
            const float lb = l2_b[c];
#pragma unroll
            for (int r = 0; r < 4; ++r)
                C[r * 128 + c] += lb + acc[r] + A[r * 128 + c];
        }
        __syncthreads();
    }
    ln_rows4(C, n3_g, n3_b, tid);   // C = final tgt
    __syncthreads();

    // ---- phase 5: fused = [F, C] @ fu_w + fu_b; BN partials --------------
    {
        const int c = tid & 63, rg = tid >> 6;   // one row per thread-group
        float acc = fu_b[c];
        const float* wA = fu_w + c;               // rows 0..63 (features half)
        for (int j4 = 0; j4 < 16; ++j4) {
            float w0 = wA[(j4 * 4 + 0) * 64], w1 = wA[(j4 * 4 + 1) * 64];
            float w2 = wA[(j4 * 4 + 2) * 64], w3 = wA[(j4 * 4 + 3) * 64];
            float4 t = *(const float4*)(&F[rg * 64 + j4 * 4]);
            acc += t.x * w0 + t.y * w1 + t.z * w2 + t.w * w3;
        }
        const float* wB = fu_w + 64 * 64 + c;     // rows 64..191 (tgt half)
        for (int j4 = 0; j4 < 32; ++j4) {
            float w0 = wB[(j4 * 4 + 0) * 64], w1 = wB[(j4 * 4 + 1) * 64];
            float w2 = wB[(j4 * 4 + 2) * 64], w3 = wB[(j4 * 4 + 3) * 64];
            float4 t = *(const float4*)(&C[rg * 128 + j4 * 4]);
            acc += t.x * w0 + t.y * w1 + t.z * w2 + t.w * w3;
        }
        fused[(r0 + rg) * 64 + c] = acc;
        H[rg * 64 + c] = acc;
    }
    __syncthreads();
    if (tid < 64) {
        float s = 0.f, s2 = 0.f;
#pragma unroll
        for (int r = 0; r < 4; ++r) { float x = H[r * 64 + tid]; s += x; s2 += x * x; }
        atomicAdd(&bnSum[tid], s);
        atomicAdd(&bnSq[tid], s2);
    }
}

// ---------------------------------------------------------------------------
// K5: batchnorm (train-mode stats) + relu -> fp32 out
// ---------------------------------------------------------------------------
__global__ __launch_bounds__(256) void k5_bn_cst(
    const float* __restrict__ fused, const float* __restrict__ bnSum,
    const float* __restrict__ bnSq,
    const float* __restrict__ g, const float* __restrict__ b,
    float* __restrict__ out, int N)
{
    const int total = N * 64;
    const float invN = 1.f / (float)N;
    for (int i = blockIdx.x * 256 + threadIdx.x; i < total; i += gridDim.x * 256) {
        int c = i & 63;
        float mu = bnSum[c] * invN;
        float var = bnSq[c] * invN - mu * mu;
        float x = fused[i];
        float y = (x - mu) * rsqrtf(var + 1e-3f) * g[c] + b[c];
        out[i] = relu(y);
    }
}

// ---------------------------------------------------------------------------
extern "C" void kernel_launch(void* const* d_in, const int* in_sizes, int n_in,
                              void* d_out, int out_size, void* d_ws, size_t ws_size,
                              hipStream_t stream)
{
    const float* features = (const float*)d_in[0];
    const int*   coords   = (const int*)d_in[1];
    const float* pe_w1 = (const float*)d_in[2];
    const float* pe_b1 = (const float*)d_in[3];
    const float* pe_w2 = (const float*)d_in[4];
    const float* pe_b2 = (const float*)d_in[5];
    const float* in_w  = (const float*)d_in[6];
    const float* in_b  = (const float*)d_in[7];
    const float* q_w   = (const float*)d_in[8];
    const float* q_b   = (const float*)d_in[9];
    const float* k_w   = (const float*)d_in[10];
    const float* k_b   = (const float*)d_in[11];
    const float* v_w   = (const float*)d_in[12];
    const float* v_b   = (const float*)d_in[13];
    const float* o_w   = (const float*)d_in[14];
    const float* o_b   = (const float*)d_in[15];
    const float* n1_g  = (const float*)d_in[16];
    const float* n1_b  = (const float*)d_in[17];
    const float* l1_w  = (const float*)d_in[18];
    const float* l1_b  = (const float*)d_in[19];
    const float* l2_w  = (const float*)d_in[20];
    const float* l2_b  = (const float*)d_in[21];
    const float* n3_g  = (const float*)d_in[22];
    const float* n3_b  = (const float*)d_in[23];
    const float* fu_w  = (const float*)d_in[24];
    const float* fu_b  = (const float*)d_in[25];
    const float* bn_g  = (const float*)d_in[26];
    const float* bn_b  = (const float*)d_in[27];

    const int N = in_sizes[0] / 64;   // 8192

    float* src   = (float*)d_ws;            // N*128
    float* qs    = src + (size_t)N * 128;   // N*128
    float* ks    = qs  + (size_t)N * 128;   // N*128
    float* vs    = ks  + (size_t)N * 128;   // N*128
    float* fused = vs  + (size_t)N * 128;   // N*64
    int*   nbr    = (int*)(fused + (size_t)N * 64);   // N*16 ints
    float* bnSum  = (float*)(nbr + (size_t)N * 16);   // 64
    float* bnSq   = bnSum + 64;                       // 64 (contiguous 128)

    // ka: N/4 src blocks + N/16 nbr blocks, interleaved 4:1 via bx%5
    ka_pre_cst<<<N / 4 + N / 16, 256, 0, stream>>>(features, coords,
                                                   pe_w1, pe_b1, pe_w2, pe_b2,
                                                   in_w, in_b, q_w, k_w, v_w,
                                                   src, qs, ks, vs, nbr, bnSum, N);
    k4_main_cst<<<N / 4, 256, 0, stream>>>(features, src, qs, ks, vs, nbr,
                                           q_b, k_b, v_b, o_w, o_b, n1_g, n1_b,
                                           l1_w, l1_b, l2_w, l2_b, n3_g, n3_b,
                                           fu_w, fu_b, fused, bnSum, bnSq);
    k5_bn_cst<<<512, 256, 0, stream>>>(fused, bnSum, bnSq, bn_g, bn_b,
                                       (float*)d_out, N);
}

// Round 5
// 259.721 us; speedup vs baseline: 1.2360x; 1.2360x over previous
//
#include <hip/hip_runtime.h>

#define DEVFN __device__ __forceinline__

// NaN-propagating relu (fmaxf(NaN,0)==0 would mask upstream failures).
DEVFN float relu(float x) { return x < 0.f ? 0.f : x; }

// ---------------------------------------------------------------------------
// KA: fused pre-work, roles interleaved bx%3: 0,1 src (8 rows), 2 nbr.
// 128-thread blocks: DS/weight wave-instruction totals scale with waves/block
// (rounds 0-4 evidence); 2 waves halves issue vs round-0's 4 while keeping
// 8 rows amortizing every weight load. Inner loops stay round-0 style:
// scalar weight streams, float4 LDS broadcasts, no unroll pragmas
// (round-2: full-unroll hoist spills; round-3: unroll(1) serializes).
// ---------------------------------------------------------------------------
__global__ __launch_bounds__(128, 3) void ka_pre_cst(
    const float* __restrict__ features, const int* __restrict__ coords,
    const float* __restrict__ pe_w1, const float* __restrict__ pe_b1,
    const float* __restrict__ pe_w2, const float* __restrict__ pe_b2,
    const float* __restrict__ in_w, const float* __restrict__ in_b,
    const float* __restrict__ q_w, const float* __restrict__ k_w,
    const float* __restrict__ v_w,
    float* __restrict__ src,
    float* __restrict__ qs, float* __restrict__ ks, float* __restrict__ vs,
    int* __restrict__ nbr, float* __restrict__ bnAcc, int N)
{
    // src-role LDS
    __shared__ __align__(16) float sF[512];   // 8 x 64 features
    __shared__ __align__(16) float sH[512];   // 8 x 64 pe-hidden
    __shared__ __align__(16) float S[1024];   // 8 x 128 src
    __shared__ int   sC[24];
    // nbr-role LDS
    __shared__ int cnt[16];
    __shared__ int lst[16 * 64];
    __shared__ int outL[256];

    const int tid = threadIdx.x;
    const int bx = blockIdx.x;
    const int role_nbr = (bx % 3) == 2;

    if (role_nbr) {
        // ---------------- nbr role: neighbor search -----------------------
        const int nb = bx / 3;
        const int q0 = nb * 16;
        if (nb == 0 && tid < 128) bnAcc[tid] = 0.f;
        if (tid < 16) cnt[tid] = 0;
        for (int i = tid; i < 256; i += 128) outL[i] = -1;
        __syncthreads();
        int qx[16], qy[16], qz[16];
#pragma unroll
        for (int q = 0; q < 16; ++q) {
            qx[q] = coords[(q0 + q) * 3 + 0];
            qy[q] = coords[(q0 + q) * 3 + 1];
            qz[q] = coords[(q0 + q) * 3 + 2];
        }
        for (int cd = tid; cd < N; cd += 128) {
            int cx = coords[cd * 3 + 0];
            int cy = coords[cd * 3 + 1];
            int cz = coords[cd * 3 + 2];
#pragma unroll
            for (int q = 0; q < 16; ++q) {
                int dx = cx - qx[q]; dx = dx < 0 ? -dx : dx;
                int dy = cy - qy[q]; dy = dy < 0 ? -dy : dy;
                int dz = cz - qz[q]; dz = dz < 0 ? -dz : dz;
                int d = dx + dy + dz;
                if (d <= 4) {
                    int s = atomicAdd(&cnt[q], 1);
                    if (s < 64) lst[q * 64 + s] = (d << 13) | cd;
                }
            }
        }
        __syncthreads();
        {
            const int q = tid >> 3, t = tid & 7;
            int n = cnt[q]; if (n > 64) n = 64;
            for (int e = t; e < n; e += 8) {
                int key = lst[q * 64 + e];
                int rank = 0;
                for (int j = 0; j < n; ++j) rank += (lst[q * 64 + j] < key) ? 1 : 0;
                if (rank < 16) outL[q * 16 + rank] = key & 8191;
            }
        }
        __syncthreads();
        for (int i = tid; i < 256; i += 128) {
            int q = i >> 4, t = i & 15;
            nbr[(q0 + q) * 16 + t] = outL[i];
        }
        return;
    }

    // ---------------- src role: 8 rows; src + q/k/v projections -----------
    const int sidx = (bx / 3) * 2 + (bx % 3);   // 0..1023
    const int r0 = sidx * 8;
    if (tid < 24) sC[tid] = coords[r0 * 3 + tid];
    for (int i = tid; i < 512; i += 128) sF[i] = features[r0 * 64 + i];
    __syncthreads();
    for (int i = tid; i < 512; i += 128) {
        int r = i >> 6, t = i & 63;
        float v0 = sC[r * 3 + 0] * (1.f / 95.f);
        float v1 = sC[r * 3 + 1] * (1.f / 95.f);
        float v2 = sC[r * 3 + 2] * (1.f / 95.f);
        float h = v0 * pe_w1[t] + v1 * pe_w1[64 + t] + v2 * pe_w1[128 + t] + pe_b1[t];
        sH[i] = relu(h);
    }
    __syncthreads();
    const int c = tid;   // 0..127, one output column per thread
    {
        // src = sF @ in_w + sH @ pe_w2 + (in_b + pe_b2); acc over 8 rows
        float acc[8];
        const float base = in_b[c] + pe_b2[c];
#pragma unroll
        for (int r = 0; r < 8; ++r) acc[r] = base;
        for (int j4 = 0; j4 < 16; ++j4) {
            float i0 = in_w[(j4 * 4 + 0) * 128 + c];
            float i1 = in_w[(j4 * 4 + 1) * 128 + c];
            float i2 = in_w[(j4 * 4 + 2) * 128 + c];
            float i3 = in_w[(j4 * 4 + 3) * 128 + c];
            float p0 = pe_w2[(j4 * 4 + 0) * 128 + c];
            float p1 = pe_w2[(j4 * 4 + 1) * 128 + c];
            float p2 = pe_w2[(j4 * 4 + 2) * 128 + c];
            float p3 = pe_w2[(j4 * 4 + 3) * 128 + c];
#pragma unroll
            for (int r = 0; r < 8; ++r) {
                float4 f = *(const float4*)(&sF[r * 64 + j4 * 4]);
                float4 h = *(const float4*)(&sH[r * 64 + j4 * 4]);
                acc[r] += f.x * i0 + f.y * i1 + f.z * i2 + f.w * i3
                        + h.x * p0 + h.y * p1 + h.z * p2 + h.w * p3;
            }
        }
#pragma unroll
        for (int r = 0; r < 8; ++r) {
            src[(r0 + r) * 128 + c] = acc[r];
            S[r * 128 + c] = acc[r];
        }
    }
    __syncthreads();
    // q/k/v in one pass: 12 concurrent weight streams, 8-row accumulators
    {
        float aq[8], ak[8], av[8];
#pragma unroll
        for (int r = 0; r < 8; ++r) { aq[r] = 0.f; ak[r] = 0.f; av[r] = 0.f; }
        for (int k4 = 0; k4 < 32; ++k4) {
            float wq0 = q_w[(k4 * 4 + 0) * 128 + c];
            float wq1 = q_w[(k4 * 4 + 1) * 128 + c];
            float wq2 = q_w[(k4 * 4 + 2) * 128 + c];
            float wq3 = q_w[(k4 * 4 + 3) * 128 + c];
            float wk0 = k_w[(k4 * 4 + 0) * 128 + c];
            float wk1 = k_w[(k4 * 4 + 1) * 128 + c];
            float wk2 = k_w[(k4 * 4 + 2) * 128 + c];
            float wk3 = k_w[(k4 * 4 + 3) * 128 + c];
            float wv0 = v_w[(k4 * 4 + 0) * 128 + c];
            float wv1 = v_w[(k4 * 4 + 1) * 128 + c];
            float wv2 = v_w[(k4 * 4 + 2) * 128 + c];
            float wv3 = v_w[(k4 * 4 + 3) * 128 + c];
#pragma unroll
            for (int r = 0; r < 8; ++r) {
                float4 s = *(const float4*)(&S[r * 128 + k4 * 4]);
                aq[r] += s.x * wq0 + s.y * wq1 + s.z * wq2 + s.w * wq3;
                ak[r] += s.x * wk0 + s.y * wk1 + s.z * wk2 + s.w * wk3;
                av[r] += s.x * wv0 + s.y * wv1 + s.z * wv2 + s.w * wv3;
            }
        }
#pragma unroll
        for (int r = 0; r < 8; ++r) {
            qs[(r0 + r) * 128 + c] = aq[r];
            ks[(r0 + r) * 128 + c] = ak[r];
            vs[(r0 + r) * 128 + c] = av[r];
        }
    }
}

// ---------------------------------------------------------------------------
// K4: attention + o-proj + LN1 + FFN + LN2 + fusion + BN partials.
// 8 rows/block, 128 threads (2 waves), 1024 blocks. Column-mapped GEMM
// phases, no K-splits (no partial staging, fewer barriers). LDS trimmed to
// ~22.5 KB via Q/SC/bias <-> H union -> ~7 blocks/CU.
// ---------------------------------------------------------------------------
DEVFN void ln_rows8_128(float* Cb, const float* __restrict__ g,
                        const float* __restrict__ b, int tid)
{
    // row = tid>>4 (8 rows x 16 threads), each thread 8 cols l*8..l*8+7
    const int r = tid >> 4, l = tid & 15;
    float4 x0 = *(const float4*)(&Cb[r * 128 + l * 8]);
    float4 x1 = *(const float4*)(&Cb[r * 128 + l * 8 + 4]);
    float s  = x0.x + x0.y + x0.z + x0.w + x1.x + x1.y + x1.z + x1.w;
    float s2 = x0.x * x0.x + x0.y * x0.y + x0.z * x0.z + x0.w * x0.w
             + x1.x * x1.x + x1.y * x1.y + x1.z * x1.z + x1.w * x1.w;
#pragma unroll
    for (int o = 1; o < 16; o <<= 1) { s += __shfl_xor(s, o); s2 += __shfl_xor(s2, o); }
    float mu = s * (1.f / 128.f);
    float var = s2 * (1.f / 128.f) - mu * mu;
    float rstd = rsqrtf(var + 1e-5f);
    const int cc = l * 8;
    float4 g0 = *(const float4*)(g + cc), g1 = *(const float4*)(g + cc + 4);
    float4 b0 = *(const float4*)(b + cc), b1 = *(const float4*)(b + cc + 4);
    float4 y0, y1;
    y0.x = (x0.x - mu) * rstd * g0.x + b0.x;
    y0.y = (x0.y - mu) * rstd * g0.y + b0.y;
    y0.z = (x0.z - mu) * rstd * g0.z + b0.z;
    y0.w = (x0.w - mu) * rstd * g0.w + b0.w;
    y1.x = (x1.x - mu) * rstd * g1.x + b1.x;
    y1.y = (x1.y - mu) * rstd * g1.y + b1.y;
    y1.z = (x1.z - mu) * rstd * g1.z + b1.z;
    y1.w = (x1.w - mu) * rstd * g1.w + b1.w;
    *(float4*)(&Cb[r * 128 + cc]) = y0;
    *(float4*)(&Cb[r * 128 + cc + 4]) = y1;
}

__global__ __launch_bounds__(128, 3) void k4_main_cst(
    const float* __restrict__ features, const float* __restrict__ src,
    const float* __restrict__ qs, const float* __restrict__ ks, const float* __restrict__ vs,
    const int* __restrict__ nbr,
    const float* __restrict__ q_b, const float* __restrict__ k_b,
    const float* __restrict__ v_b,
    const float* __restrict__ o_w, const float* __restrict__ o_b,
    const float* __restrict__ n1_g, const float* __restrict__ n1_b,
    const float* __restrict__ l1_w, const float* __restrict__ l1_b,
    const float* __restrict__ l2_w, const float* __restrict__ l2_b,
    const float* __restrict__ n3_g, const float* __restrict__ n3_b,
    const float* __restrict__ fu_w, const float* __restrict__ fu_b,
    float* __restrict__ fused, float* __restrict__ bnSum, float* __restrict__ bnSq)
{
    __shared__ __align__(16) float A[1024];   // src tile; P5 BN staging
    __shared__ __align__(16) float Bt[1024];  // head_out
    __shared__ __align__(16) float C[1024];   // running activation
    __shared__ __align__(16) float F[512];    // features tile
    __shared__ __align__(16) union UN {
        struct { float Q[1024]; float SC[512]; float bK[128]; float bV[128]; } a;
        float H[2048];                        // ffn hidden (from P3 on)
    } U;
    __shared__ int idxL[128];
    const int tid = threadIdx.x;
    const int r0 = blockIdx.x * 8;

    for (int i = tid; i < 1024; i += 128) A[i] = src[r0 * 128 + i];
    for (int i = tid; i < 512; i += 128) F[i] = features[r0 * 64 + i];
    idxL[tid] = nbr[r0 * 16 + tid];
    U.a.bK[tid] = k_b[tid]; U.a.bV[tid] = v_b[tid];
    __syncthreads();
    {   // Q gather + bias: thread = (row=tid>>4, colgroup=tid&15 -> 8 cols)
        int r = tid >> 4, cg = tid & 15;
        int i0 = idxL[r * 16];
        float4 qa = make_float4(0.f, 0.f, 0.f, 0.f), qb = qa;
        if (i0 >= 0) {
            qa = *(const float4*)(qs + i0 * 128 + cg * 8);
            qb = *(const float4*)(qs + i0 * 128 + cg * 8 + 4);
        }
        float4 ba = *(const float4*)(q_b + cg * 8);
        float4 bb = *(const float4*)(q_b + cg * 8 + 4);
        qa.x += ba.x; qa.y += ba.y; qa.z += ba.z; qa.w += ba.w;
        qb.x += bb.x; qb.y += bb.y; qb.z += bb.z; qb.w += bb.w;
        *(float4*)(&U.a.Q[r * 128 + cg * 8]) = qa;
        *(float4*)(&U.a.Q[r * 128 + cg * 8 + 4]) = qb;
    }
    __syncthreads();

    // ---- phase 1a: scores. thread = (ar=tid>>4, ah=(tid>>2)&3, ag=tid&3) -
    // j = jj*4 + ag  =>  j4 = jj (neighbor slot), ch = ag (fixed per thread)
    const int ar = tid >> 4, ah = (tid >> 2) & 3;
    {
        const int ag = tid & 3;
        int id[4];
#pragma unroll
        for (int jj = 0; jj < 4; ++jj) id[jj] = idxL[ar * 16 + ah * 4 + jj];
        float s0 = 0.f, s1 = 0.f, s2 = 0.f, s3 = 0.f;
#pragma unroll
        for (int c4 = 0; c4 < 8; ++c4) {
            float4 qv = *(const float4*)(&U.a.Q[ar * 128 + ah * 32 + c4 * 4]);
            float4 kb = *(const float4*)(&U.a.bK[ag * 32 + c4 * 4]);
            float4 kv;
#pragma unroll
            for (int jj = 0; jj < 4; ++jj) {
                kv = make_float4(0.f, 0.f, 0.f, 0.f);
                if (id[jj] >= 0) kv = *(const float4*)(ks + id[jj] * 128 + ag * 32 + c4 * 4);
                float d = qv.x * (kv.x + kb.x) + qv.y * (kv.y + kb.y)
                        + qv.z * (kv.z + kb.z) + qv.w * (kv.w + kb.w);
                if (jj == 0) s0 += d; else if (jj == 1) s1 += d;
                else if (jj == 2) s2 += d; else s3 += d;
            }
        }
        const float sc = 0.08838834764831845f;  // 1/sqrt(128)
        U.a.SC[ar * 64 + ah * 16 + 0 * 4 + ag] = s0 * sc;
        U.a.SC[ar * 64 + ah * 16 + 1 * 4 + ag] = s1 * sc;
        U.a.SC[ar * 64 + ah * 16 + 2 * 4 + ag] = s2 * sc;
        U.a.SC[ar * 64 + ah * 16 + 3 * 4 + ag] = s3 * sc;
    }
    __syncthreads();

    // ---- phase 1b: softmax (redundant per 4-thread group) + P@V ----------
    // thread owns within-head cols d0 = (tid&3)*8 .. +7 (two quads).
    {
        const int ag2 = tid & 3;
        float p[16];
        float mx = -3.4e38f;
#pragma unroll
        for (int j = 0; j < 16; ++j) { p[j] = U.a.SC[ar * 64 + ah * 16 + j]; mx = fmaxf(mx, p[j]); }
        float sum = 0.f;
#pragma unroll
        for (int j = 0; j < 16; ++j) { p[j] = __expf(p[j] - mx); sum += p[j]; }
        float inv = 1.f / sum;
        // hoist bV fragments for the 4 ch values (const-indexed after unroll)
        float4 vb0[4], vb1[4];
#pragma unroll
        for (int ch = 0; ch < 4; ++ch) {
            vb0[ch] = *(const float4*)(&U.a.bV[ch * 32 + ag2 * 8]);
            vb1[ch] = *(const float4*)(&U.a.bV[ch * 32 + ag2 * 8 + 4]);
        }
        float4 a0 = make_float4(0.f, 0.f, 0.f, 0.f), a1 = a0;
#pragma unroll
        for (int j = 0; j < 16; ++j) {
            const int j4 = j >> 2, ch = j & 3;
            int id = idxL[ar * 16 + ah * 4 + j4];
            float4 v0 = make_float4(0.f, 0.f, 0.f, 0.f), v1 = v0;
            if (id >= 0) {
                v0 = *(const float4*)(vs + id * 128 + ch * 32 + ag2 * 8);
                v1 = *(const float4*)(vs + id * 128 + ch * 32 + ag2 * 8 + 4);
            }
            float w = p[j] * inv;
            a0.x += w * (v0.x + vb0[ch].x); a0.y += w * (v0.y + vb0[ch].y);
            a0.z += w * (v0.z + vb0[ch].z); a0.w += w * (v0.w + vb0[ch].w);
            a1.x += w * (v1.x + vb1[ch].x); a1.y += w * (v1.y + vb1[ch].y);
            a1.z += w * (v1.z + vb1[ch].z); a1.w += w * (v1.w + vb1[ch].w);
        }
        *(float4*)(&Bt[ar * 128 + ah * 32 + ag2 * 8]) = a0;
        *(float4*)(&Bt[ar * 128 + ah * 32 + ag2 * 8 + 4]) = a1;
    }
    __syncthreads();

    // ---- phase 2: C = A + head_out @ o_w + o_b (thread = col, acc[8]) ----
    {
        const int c = tid;
        float acc[8];
#pragma unroll
        for (int r = 0; r < 8; ++r) acc[r] = 0.f;
        for (int k4 = 0; k4 < 32; ++k4) {
            float w0 = o_w[(k4 * 4 + 0) * 128 + c];
            float w1 = o_w[(k4 * 4 + 1) * 128 + c];
            float w2 = o_w[(k4 * 4 + 2) * 128 + c];
            float w3 = o_w[(k4 * 4 + 3) * 128 + c];
#pragma unroll
            for (int r = 0; r < 8; ++r) {
                float4 t = *(const float4*)(&Bt[r * 128 + k4 * 4]);
                acc[r] += t.x * w0 + t.y * w1 + t.z * w2 + t.w * w3;
            }
        }
        const float ob = o_b[c];
#pragma unroll
        for (int r = 0; r < 8; ++r) C[r * 128 + c] = A[r * 128 + c] + ob + acc[r];
    }
    __syncthreads();
    ln_rows8_128(C, n1_g, n1_b, tid);   // C = tgt
    __syncthreads();

    // ---- phase 3: H = relu(C @ l1_w + l1_b); thread = cols {tid, tid+128} -
    {
        const int c = tid;
        float acc0[8], acc1[8];
#pragma unroll
        for (int r = 0; r < 8; ++r) { acc0[r] = 0.f; acc1[r] = 0.f; }
        for (int k4 = 0; k4 < 32; ++k4) {
            float a0 = l1_w[(k4 * 4 + 0) * 256 + c];
            float a1 = l1_w[(k4 * 4 + 1) * 256 + c];
            float a2 = l1_w[(k4 * 4 + 2) * 256 + c];
            float a3 = l1_w[(k4 * 4 + 3) * 256 + c];
            float b0 = l1_w[(k4 * 4 + 0) * 256 + c + 128];
            float b1 = l1_w[(k4 * 4 + 1) * 256 + c + 128];
            float b2 = l1_w[(k4 * 4 + 2) * 256 + c + 128];
            float b3 = l1_w[(k4 * 4 + 3) * 256 + c + 128];
#pragma unroll
            for (int r = 0; r < 8; ++r) {
                float4 t = *(const float4*)(&C[r * 128 + k4 * 4]);
                acc0[r] += t.x * a0 + t.y * a1 + t.z * a2 + t.w * a3;
                acc1[r] += t.x * b0 + t.y * b1 + t.z * b2 + t.w * b3;
            }
        }
        const float lb0 = l1_b[c], lb1 = l1_b[c + 128];
#pragma unroll
        for (int r = 0; r < 8; ++r) {
            U.H[r * 256 + c]       = relu(acc0[r] + lb0);
            U.H[r * 256 + c + 128] = relu(acc1[r] + lb1);
        }
    }
    __syncthreads();

    // ---- phase 4: C += H @ l2_w + l2_b (thread = col, acc[8], K=256) -----
    {
        const int c = tid;
        float acc[8];
#pragma unroll
        for (int r = 0; r < 8; ++r) acc[r] = 0.f;
        for (int k4 = 0; k4 < 64; ++k4) {
            float w0 = l2_w[(k4 * 4 + 0) * 128 + c];
            float w1 = l2_w[(k4 * 4 + 1) * 128 + c];
            float w2 = l2_w[(k4 * 4 + 2) * 128 + c];
            float w3 = l2_w[(k4 * 4 + 3) * 128 + c];
#pragma unroll
            for (int r = 0; r < 8; ++r) {
                float4 t = *(const float4*)(&U.H[r * 256 + k4 * 4]);
                acc[r] += t.x * w0 + t.y * w1 + t.z * w2 + t.w * w3;
            }
        }
        const float lb = l2_b[c];
#pragma unroll
        for (int r = 0; r < 8; ++r) C[r * 128 + c] += lb + acc[r];
    }
    __syncthreads();
    ln_rows8_128(C, n3_g, n3_b, tid);   // C = final tgt
    __syncthreads();

    // ---- phase 5: fused = [F, C] @ fu_w + fu_b; BN staging in A ----------
    {
        const int c = tid & 63, rh = tid >> 6;   // rows rh*4 .. rh*4+3
        float acc[4];
        const float fb = fu_b[c];
#pragma unroll
        for (int r = 0; r < 4; ++r) acc[r] = fb;
        for (int j4 = 0; j4 < 16; ++j4) {
            float w0 = fu_w[(j4 * 4 + 0) * 64 + c];
            float w1 = fu_w[(j4 * 4 + 1) * 64 + c];
            float w2 = fu_w[(j4 * 4 + 2) * 64 + c];
            float w3 = fu_w[(j4 * 4 + 3) * 64 + c];
#pragma unroll
            for (int r = 0; r < 4; ++r) {
                float4 t = *(const float4*)(&F[(rh * 4 + r) * 64 + j4 * 4]);
                acc[r] += t.x * w0 + t.y * w1 + t.z * w2 + t.w * w3;
            }
        }
        const float* wB = fu_w + 64 * 64;
        for (int j4 = 0; j4 < 32; ++j4) {
            float w0 = wB[(j4 * 4 + 0) * 64 + c];
            float w1 = wB[(j4 * 4 + 1) * 64 + c];
            float w2 = wB[(j4 * 4 + 2) * 64 + c];
            float w3 = wB[(j4 * 4 + 3) * 64 + c];
#pragma unroll
            for (int r = 0; r < 4; ++r) {
                float4 t = *(const float4*)(&C[(rh * 4 + r) * 128 + j4 * 4]);
                acc[r] += t.x * w0 + t.y * w1 + t.z * w2 + t.w * w3;
            }
        }
#pragma unroll
        for (int r = 0; r < 4; ++r) {
            int row = rh * 4 + r;
            float v = acc[r];
            fused[(r0 + row) * 64 + c] = v;
            A[row * 64 + c] = v;
        }
    }
    __syncthreads();
    if (tid < 64) {
        float s = 0.f, s2 = 0.f;
#pragma unroll
        for (int r = 0; r < 8; ++r) { float x = A[r * 64 + tid]; s += x; s2 += x * x; }
        atomicAdd(&bnSum[tid], s);
        atomicAdd(&bnSq[tid], s2);
    }
}

// ---------------------------------------------------------------------------
// K5: batchnorm (train-mode stats) + relu -> fp32 out
// ---------------------------------------------------------------------------
__global__ __launch_bounds__(256) void k5_bn_cst(
    const float* __restrict__ fused, const float* __restrict__ bnSum,
    const float* __restrict__ bnSq,
    const float* __restrict__ g, const float* __restrict__ b,
    float* __restrict__ out, int N)
{
    const int total = N * 64;
    const float invN = 1.f / (float)N;
    for (int i = blockIdx.x * 256 + threadIdx.x; i < total; i += gridDim.x * 256) {
        int c = i & 63;
        float mu = bnSum[c] * invN;
        float var = bnSq[c] * invN - mu * mu;
        float x = fused[i];
        float y = (x - mu) * rsqrtf(var + 1e-3f) * g[c] + b[c];
        out[i] = relu(y);
    }
}

// ---------------------------------------------------------------------------
extern "C" void kernel_launch(void* const* d_in, const int* in_sizes, int n_in,
                              void* d_out, int out_size, void* d_ws, size_t ws_size,
                              hipStream_t stream)
{
    const float* features = (const float*)d_in[0];
    const int*   coords   = (const int*)d_in[1];
    const float* pe_w1 = (const float*)d_in[2];
    const float* pe_b1 = (const float*)d_in[3];
    const float* pe_w2 = (const float*)d_in[4];
    const float* pe_b2 = (const float*)d_in[5];
    const float* in_w  = (const float*)d_in[6];
    const float* in_b  = (const float*)d_in[7];
    const float* q_w   = (const float*)d_in[8];
    const float* q_b   = (const float*)d_in[9];
    const float* k_w   = (const float*)d_in[10];
    const float* k_b   = (const float*)d_in[11];
    const float* v_w   = (const float*)d_in[12];
    const float* v_b   = (const float*)d_in[13];
    const float* o_w   = (const float*)d_in[14];
    const float* o_b   = (const float*)d_in[15];
    const float* n1_g  = (const float*)d_in[16];
    const float* n1_b  = (const float*)d_in[17];
    const float* l1_w  = (const float*)d_in[18];
    const float* l1_b  = (const float*)d_in[19];
    const float* l2_w  = (const float*)d_in[20];
    const float* l2_b  = (const float*)d_in[21];
    const float* n3_g  = (const float*)d_in[22];
    const float* n3_b  = (const float*)d_in[23];
    const float* fu_w  = (const float*)d_in[24];
    const float* fu_b  = (const float*)d_in[25];
    const float* bn_g  = (const float*)d_in[26];
    const float* bn_b  = (const float*)d_in[27];

    const int N = in_sizes[0] / 64;   // 8192

    float* src   = (float*)d_ws;            // N*128
    float* qs    = src + (size_t)N * 128;   // N*128
    float* ks    = qs  + (size_t)N * 128;   // N*128
    float* vs    = ks  + (size_t)N * 128;   // N*128
    float* fused = vs  + (size_t)N * 128;   // N*64
    int*   nbr    = (int*)(fused + (size_t)N * 64);   // N*16 ints
    float* bnSum  = (float*)(nbr + (size_t)N * 16);   // 64
    float* bnSq   = bnSum + 64;                       // 64 (contiguous 128)

    // ka: N/8 src blocks + N/16 nbr blocks, interleaved 2:1 via bx%3
    ka_pre_cst<<<N / 8 + N / 16, 128, 0, stream>>>(features, coords,
                                                   pe_w1, pe_b1, pe_w2, pe_b2,
                                                   in_w, in_b, q_w, k_w, v_w,
                                                   src, qs, ks, vs, nbr, bnSum, N);
    k4_main_cst<<<N / 8, 128, 0, stream>>>(features, src, qs, ks, vs, nbr,
                                           q_b, k_b, v_b, o_w, o_b, n1_g, n1_b,
                                           l1_w, l1_b, l2_w, l2_b, n3_g, n3_b,
                                           fu_w, fu_b, fused, bnSum, bnSq);
    k5_bn_cst<<<512, 256, 0, stream>>>(fused, bnSum, bnSq, bn_g, bn_b,
                                       (float*)d_out, N);
}

// Round 6
// 209.274 us; speedup vs baseline: 1.5339x; 1.2411x over previous
//
#include <hip/hip_runtime.h>

#define DEVFN __device__ __forceinline__

// NaN-propagating relu (fmaxf(NaN,0)==0 would mask upstream failures).
DEVFN float relu(float x) { return x < 0.f ? 0.f : x; }

// f16 pair helpers: weights/activations packed as half2 in k-major pairs.
// v_dot2_f32_f16: 2 MACs per instr, f32 accumulate.
typedef _Float16 h2 __attribute__((ext_vector_type(2)));
DEVFN float dot2(unsigned a, unsigned b, float c) {
    return __builtin_amdgcn_fdot2(__builtin_bit_cast(h2, a),
                                  __builtin_bit_cast(h2, b), c, false);
}
DEVFN unsigned pack2(float x, float y) {
    h2 h; h.x = (_Float16)x; h.y = (_Float16)y;
    return __builtin_bit_cast(unsigned, h);
}

// Packed-weight layout: W (K x C, k-major) -> PW[kp*C + c] = half2(W[2kp][c], W[2kp+1][c]).
// Offsets (in dwords) inside the packed-weight workspace region:
#define OFF_Q   0
#define OFF_K   8192
#define OFF_V   16384
#define OFF_O   24576
#define OFF_L1  32768
#define OFF_L2  49152
#define OFF_IN  65536
#define OFF_PE  69632
#define OFF_FU  73728
#define PACKED_TOTAL 79872

// ---------------------------------------------------------------------------
// K0: pack all weight matrices to half2 (runs once before ka).
// ---------------------------------------------------------------------------
__global__ __launch_bounds__(256) void k0_pack(
    const float* __restrict__ q_w, const float* __restrict__ k_w,
    const float* __restrict__ v_w, const float* __restrict__ o_w,
    const float* __restrict__ l1_w, const float* __restrict__ l2_w,
    const float* __restrict__ in_w, const float* __restrict__ pe_w2,
    const float* __restrict__ fu_w, unsigned* __restrict__ dst)
{
    const int gid = blockIdx.x * 256 + threadIdx.x;
    const int stride = gridDim.x * 256;
    auto packmat = [&](const float* s, int K, int C, unsigned* d) {
        const int n = (K / 2) * C;
        for (int i = gid; i < n; i += stride) {
            int kp = i / C, c = i - kp * C;
            d[i] = pack2(s[(2 * kp) * C + c], s[(2 * kp + 1) * C + c]);
        }
    };
    packmat(q_w, 128, 128, dst + OFF_Q);
    packmat(k_w, 128, 128, dst + OFF_K);
    packmat(v_w, 128, 128, dst + OFF_V);
    packmat(o_w, 128, 128, dst + OFF_O);
    packmat(l1_w, 128, 256, dst + OFF_L1);
    packmat(l2_w, 256, 128, dst + OFF_L2);
    packmat(in_w, 64, 128, dst + OFF_IN);
    packmat(pe_w2, 64, 128, dst + OFF_PE);
    packmat(fu_w, 192, 64, dst + OFF_FU);
}

// ---------------------------------------------------------------------------
// KA: fused pre-work, two block roles interleaved (bx%3): 2/3 src, 1/3 nbr.
//  src role : src = features@in_w+in_b + relu(pe)@pe_w2+pe_b2 ; qs/ks/vs
//  nbr role : neighbor top-16 (manhattan<=4, stable); nbr-block 0 zeros BN.
// Round-0 structure; GEMM inner loops on f16-pair dot2 (half the LDS reads,
// half the MAC instrs, half the weight loads — the measured round-0 wall was
// the LDS pipe: ~740 ds_read_b128/thread x 16 waves/CU x ~12cy ~= 59us).
// ---------------------------------------------------------------------------
__global__ __launch_bounds__(256, 4) void ka_pre_cst(
    const float* __restrict__ features, const int* __restrict__ coords,
    const float* __restrict__ pe_w1, const float* __restrict__ pe_b1,
    const float* __restrict__ pe_b2,
    const float* __restrict__ in_b,
    const unsigned* __restrict__ wH,          // packed weights
    float* __restrict__ src,
    float* __restrict__ qs, float* __restrict__ ks, float* __restrict__ vs,
    int* __restrict__ nbr, float* __restrict__ bnAcc, int N)
{
    // src-role LDS
    __shared__ __align__(16) float S[1024];       // 8 x 128 src f32
    __shared__ __align__(16) unsigned SH[512];    // 8 x 64 src packed
    __shared__ __align__(16) unsigned FHp[256];   // 8 x 32 features packed
    __shared__ __align__(16) unsigned HHp[256];   // 8 x 32 pe-hidden packed
    __shared__ int   sC[24];
    // nbr-role LDS
    __shared__ int cnt[16];
    __shared__ int lst[16 * 64];
    __shared__ int outL[256];

    const int tid = threadIdx.x;
    const int bx = blockIdx.x;
    const int role_nbr = (bx % 3) == 2;

    if (role_nbr) {
        // ---------------- nbr role: neighbor search -----------------------
        const int nb = bx / 3;
        const int q0 = nb * 16;
        if (nb == 0 && tid < 128) bnAcc[tid] = 0.f;
        if (tid < 16) cnt[tid] = 0;
        outL[tid] = -1;
        __syncthreads();
        int qx[16], qy[16], qz[16];
#pragma unroll
        for (int q = 0; q < 16; ++q) {
            qx[q] = coords[(q0 + q) * 3 + 0];
            qy[q] = coords[(q0 + q) * 3 + 1];
            qz[q] = coords[(q0 + q) * 3 + 2];
        }
        for (int cd = tid; cd < N; cd += 256) {
            int cx = coords[cd * 3 + 0];
            int cy = coords[cd * 3 + 1];
            int cz = coords[cd * 3 + 2];
#pragma unroll
            for (int q = 0; q < 16; ++q) {
                int dx = cx - qx[q]; dx = dx < 0 ? -dx : dx;
                int dy = cy - qy[q]; dy = dy < 0 ? -dy : dy;
                int dz = cz - qz[q]; dz = dz < 0 ? -dz : dz;
                int d = dx + dy + dz;
                if (d <= 4) {
                    int s = atomicAdd(&cnt[q], 1);
                    if (s < 64) lst[q * 64 + s] = (d << 13) | cd;
                }
            }
        }
        __syncthreads();
        {
            const int q = tid >> 4, t = tid & 15;
            int n = cnt[q]; if (n > 64) n = 64;
            for (int e = t; e < n; e += 16) {
                int key = lst[q * 64 + e];
                int rank = 0;
                for (int j = 0; j < n; ++j) rank += (lst[q * 64 + j] < key) ? 1 : 0;
                if (rank < 16) outL[q * 16 + rank] = key & 8191;
            }
        }
        __syncthreads();
        {
            const int q = tid >> 4, t = tid & 15;
            nbr[(q0 + q) * 16 + t] = outL[q * 16 + t];
        }
        return;
    }

    // ---------------- src role: src + q/k/v projections -------------------
    const int sb = (bx / 3) * 2 + (bx % 3);   // 0..1023
    const int r0 = sb * 8;
    if (tid < 24) sC[tid] = coords[r0 * 3 + tid];
    if (tid < 256) {   // features 8x64 -> packed pairs
        float2 f = *(const float2*)(features + r0 * 64 + tid * 2);
        FHp[tid] = pack2(f.x, f.y);
    }
    __syncthreads();
    if (tid < 256) {   // pe hidden, 2 cols per thread, packed
        int r = tid >> 5, t2 = (tid & 31) * 2;
        float v0 = sC[r * 3 + 0] * (1.f / 95.f);
        float v1 = sC[r * 3 + 1] * (1.f / 95.f);
        float v2 = sC[r * 3 + 2] * (1.f / 95.f);
        float h0 = v0 * pe_w1[t2] + v1 * pe_w1[64 + t2] + v2 * pe_w1[128 + t2] + pe_b1[t2];
        float h1 = v0 * pe_w1[t2 + 1] + v1 * pe_w1[64 + t2 + 1] + v2 * pe_w1[128 + t2 + 1] + pe_b1[t2 + 1];
        HHp[tid] = pack2(relu(h0), relu(h1));
    }
    __syncthreads();
    const int c = tid & 127, rh = tid >> 7;
    {
        // src = F@in_w + H@pe_w2 + (in_b + pe_b2), dot2 pairs, K=64 -> 32 dw
        const unsigned* inH = wH + OFF_IN;
        const unsigned* peH = wH + OFF_PE;
        float acc[4];
        const float base = in_b[c] + pe_b2[c];
#pragma unroll
        for (int r = 0; r < 4; ++r) acc[r] = base;
        for (int kp4 = 0; kp4 < 8; ++kp4) {
            unsigned i0 = inH[(kp4 * 4 + 0) * 128 + c];
            unsigned i1 = inH[(kp4 * 4 + 1) * 128 + c];
            unsigned i2 = inH[(kp4 * 4 + 2) * 128 + c];
            unsigned i3 = inH[(kp4 * 4 + 3) * 128 + c];
            unsigned p0 = peH[(kp4 * 4 + 0) * 128 + c];
            unsigned p1 = peH[(kp4 * 4 + 1) * 128 + c];
            unsigned p2 = peH[(kp4 * 4 + 2) * 128 + c];
            unsigned p3 = peH[(kp4 * 4 + 3) * 128 + c];
#pragma unroll
            for (int r = 0; r < 4; ++r) {
                const int rr = rh * 4 + r;
                uint4 f = *(const uint4*)(&FHp[rr * 32 + kp4 * 4]);
                uint4 h = *(const uint4*)(&HHp[rr * 32 + kp4 * 4]);
                acc[r] = dot2(f.x, i0, acc[r]); acc[r] = dot2(f.y, i1, acc[r]);
                acc[r] = dot2(f.z, i2, acc[r]); acc[r] = dot2(f.w, i3, acc[r]);
                acc[r] = dot2(h.x, p0, acc[r]); acc[r] = dot2(h.y, p1, acc[r]);
                acc[r] = dot2(h.z, p2, acc[r]); acc[r] = dot2(h.w, p3, acc[r]);
            }
        }
#pragma unroll
        for (int r = 0; r < 4; ++r) {
            src[(r0 + rh * 4 + r) * 128 + c] = acc[r];
            S[(rh * 4 + r) * 128 + c] = acc[r];
        }
    }
    __syncthreads();
    // pack S -> SH (pairs along the col axis, which is K for q/k/v)
    for (int i = tid; i < 512; i += 256) {
        float2 s = *(const float2*)(&S[i * 2]);
        SH[i] = pack2(s.x, s.y);
    }
    __syncthreads();
    // q/k/v in one pass: 12 packed weight streams, dot2
    {
        const unsigned* qH = wH + OFF_Q;
        const unsigned* kH = wH + OFF_K;
        const unsigned* vH = wH + OFF_V;
        float aq[4], ak[4], av[4];
#pragma unroll
        for (int r = 0; r < 4; ++r) { aq[r] = 0.f; ak[r] = 0.f; av[r] = 0.f; }
        for (int kp4 = 0; kp4 < 16; ++kp4) {
            unsigned q0 = qH[(kp4 * 4 + 0) * 128 + c];
            unsigned q1 = qH[(kp4 * 4 + 1) * 128 + c];
            unsigned q2 = qH[(kp4 * 4 + 2) * 128 + c];
            unsigned q3 = qH[(kp4 * 4 + 3) * 128 + c];
            unsigned k0 = kH[(kp4 * 4 + 0) * 128 + c];
            unsigned k1 = kH[(kp4 * 4 + 1) * 128 + c];
            unsigned k2 = kH[(kp4 * 4 + 2) * 128 + c];
            unsigned k3 = kH[(kp4 * 4 + 3) * 128 + c];
            unsigned v0 = vH[(kp4 * 4 + 0) * 128 + c];
            unsigned v1 = vH[(kp4 * 4 + 1) * 128 + c];
            unsigned v2 = vH[(kp4 * 4 + 2) * 128 + c];
            unsigned v3 = vH[(kp4 * 4 + 3) * 128 + c];
#pragma unroll
            for (int r = 0; r < 4; ++r) {
                uint4 s4 = *(const uint4*)(&SH[(rh * 4 + r) * 64 + kp4 * 4]);
                aq[r] = dot2(s4.x, q0, aq[r]); aq[r] = dot2(s4.y, q1, aq[r]);
                aq[r] = dot2(s4.z, q2, aq[r]); aq[r] = dot2(s4.w, q3, aq[r]);
                ak[r] = dot2(s4.x, k0, ak[r]); ak[r] = dot2(s4.y, k1, ak[r]);
                ak[r] = dot2(s4.z, k2, ak[r]); ak[r] = dot2(s4.w, k3, ak[r]);
                av[r] = dot2(s4.x, v0, av[r]); av[r] = dot2(s4.y, v1, av[r]);
                av[r] = dot2(s4.z, v2, av[r]); av[r] = dot2(s4.w, v3, av[r]);
            }
        }
#pragma unroll
        for (int r = 0; r < 4; ++r) {
            qs[(r0 + rh * 4 + r) * 128 + c] = aq[r];
            ks[(r0 + rh * 4 + r) * 128 + c] = ak[r];
            vs[(r0 + rh * 4 + r) * 128 + c] = av[r];
        }
    }
}

// ---------------------------------------------------------------------------
// K4: attention + o-proj + LN1 + FFN + LN2 + fusion + BN partials.
// Round-0 structure (8 rows/block, 1024 blocks, 4/CU, 16 waves/CU); GEMM
// phases on dot2 with packed activations; P2/P4 full-K per thread (no
// K-split staging, 2 fewer barriers); attention k/v biases folded out of
// the inner loops (q.kb hoisted; sum(w)=1 => +vb once).
// ---------------------------------------------------------------------------
DEVFN void ln_rows8_pack(float* Cb, unsigned* CHp, const float* __restrict__ g,
                         const float* __restrict__ b, int tid)
{
    const int r = tid >> 5, l = tid & 31;
    float x[4]; float s = 0.f, s2 = 0.f;
#pragma unroll
    for (int i = 0; i < 4; ++i) {
        x[i] = Cb[r * 128 + l * 4 + i];
        s += x[i]; s2 += x[i] * x[i];
    }
#pragma unroll
    for (int o = 1; o < 32; o <<= 1) { s += __shfl_xor(s, o); s2 += __shfl_xor(s2, o); }
    float mu = s * (1.f / 128.f);
    float var = s2 * (1.f / 128.f) - mu * mu;
    float rstd = rsqrtf(var + 1e-5f);
    float y[4];
#pragma unroll
    for (int i = 0; i < 4; ++i) {
        int cc = l * 4 + i;
        y[i] = (x[i] - mu) * rstd * g[cc] + b[cc];
        Cb[r * 128 + cc] = y[i];
    }
    CHp[r * 64 + l * 2]     = pack2(y[0], y[1]);
    CHp[r * 64 + l * 2 + 1] = pack2(y[2], y[3]);
}

__global__ __launch_bounds__(256, 4) void k4_main_cst(
    const float* __restrict__ features, const float* __restrict__ src,
    const float* __restrict__ qs, const float* __restrict__ ks, const float* __restrict__ vs,
    const int* __restrict__ nbr,
    const float* __restrict__ q_b, const float* __restrict__ k_b,
    const float* __restrict__ v_b,
    const unsigned* __restrict__ wH,
    const float* __restrict__ o_b,
    const float* __restrict__ n1_g, const float* __restrict__ n1_b,
    const float* __restrict__ l1_b,
    const float* __restrict__ l2_b,
    const float* __restrict__ n3_g, const float* __restrict__ n3_b,
    const float* __restrict__ fu_b,
    float* __restrict__ fused, float* __restrict__ bnSum, float* __restrict__ bnSq)
{
    __shared__ __align__(16) float A[1024];        // src tile; P5 BN staging
    __shared__ __align__(16) float C[1024];        // running activation f32
    __shared__ __align__(16) float Q[1024];        // q rows (bias applied)
    __shared__ __align__(16) float SC[512];        // attention scores
    __shared__ __align__(16) unsigned BtH[512];    // head_out packed 8x64
    __shared__ __align__(16) unsigned CH[512];     // tgt packed 8x64
    __shared__ __align__(16) unsigned FH[256];     // features packed 8x32
    __shared__ __align__(16) _Float16 Hh[2048];    // ffn hidden f16 8x256
    __shared__ __align__(16) float bK[128], bV[128];
    __shared__ int idxL[128];
    const int tid = threadIdx.x;
    const int r0 = blockIdx.x * 8;

    for (int i = tid; i < 1024; i += 256) A[i] = src[r0 * 128 + i];
    if (tid < 256) {
        float2 f = *(const float2*)(features + r0 * 64 + tid * 2);
        FH[tid] = pack2(f.x, f.y);
    }
    if (tid < 128) {
        idxL[tid] = nbr[r0 * 16 + tid];
        bK[tid] = k_b[tid]; bV[tid] = v_b[tid];
    }
    __syncthreads();
    {   // vectorized Q gather + bias: thread = (row=tid>>5, colgroup=tid&31)
        int r = tid >> 5, cg = tid & 31;
        int i0 = idxL[r * 16];
        float4 qv = make_float4(0.f, 0.f, 0.f, 0.f);
        if (i0 >= 0) qv = *(const float4*)(qs + i0 * 128 + cg * 4);
        float4 qb = *(const float4*)(q_b + cg * 4);
        qv.x += qb.x; qv.y += qb.y; qv.z += qb.z; qv.w += qb.w;
        *(float4*)(&Q[r * 128 + cg * 4]) = qv;
    }
    __syncthreads();

    // ---- phase 1a: scores. thread = (row r, head h, group g of 8) --------
    // s_j = q.(k_j + kb) = q.k_j + q.kb ; q.kb hoisted (same ch for both j).
    const int ar = tid >> 5, ah = (tid >> 3) & 3, ag = tid & 7;
    {
        const int ch = ag & 3;
        float sbias = 0.f;
#pragma unroll
        for (int c4 = 0; c4 < 8; ++c4) {
            float4 qv = *(const float4*)(&Q[ar * 128 + ah * 32 + c4 * 4]);
            float4 kb = *(const float4*)(&bK[ch * 32 + c4 * 4]);
            sbias += qv.x * kb.x + qv.y * kb.y + qv.z * kb.z + qv.w * kb.w;
        }
#pragma unroll
        for (int jj = 0; jj < 2; ++jj) {
            int j = ag + jj * 8;
            int j4 = j >> 2;
            int id = idxL[ar * 16 + ah * 4 + j4];
            float s = 0.f;
            if (id >= 0) {
#pragma unroll
                for (int c4 = 0; c4 < 8; ++c4) {
                    float4 qv = *(const float4*)(&Q[ar * 128 + ah * 32 + c4 * 4]);
                    float4 kv = *(const float4*)(ks + id * 128 + ch * 32 + c4 * 4);
                    s += qv.x * kv.x + qv.y * kv.y + qv.z * kv.z + qv.w * kv.w;
                }
            }
            SC[ar * 64 + ah * 16 + j] = (s + sbias) * 0.08838834764831845f;
        }
    }
    __syncthreads();

    // ---- phase 1b: softmax + P@V (sum w = 1 => +vb once); packed write ---
    {
        float p[16];
        float mx = -3.4e38f;
#pragma unroll
        for (int j = 0; j < 16; ++j) { p[j] = SC[ar * 64 + ah * 16 + j]; mx = fmaxf(mx, p[j]); }
        float sum = 0.f;
#pragma unroll
        for (int j = 0; j < 16; ++j) { p[j] = __expf(p[j] - mx); sum += p[j]; }
        float inv = 1.f / sum;
        float4 acc = make_float4(0.f, 0.f, 0.f, 0.f);
#pragma unroll
        for (int j = 0; j < 16; ++j) {
            int j4 = j >> 2, ch = j & 3;
            int id = idxL[ar * 16 + ah * 4 + j4];
            float w = p[j] * inv;
            if (id >= 0) {
                float4 vv = *(const float4*)(vs + id * 128 + ch * 32 + ag * 4);
                acc.x += w * vv.x; acc.y += w * vv.y;
                acc.z += w * vv.z; acc.w += w * vv.w;
            }
        }
        float4 vb = *(const float4*)(&bV[ah * 32 + ag * 4]);
        acc.x += vb.x; acc.y += vb.y; acc.z += vb.z; acc.w += vb.w;
        BtH[ar * 64 + ah * 16 + ag * 2]     = pack2(acc.x, acc.y);
        BtH[ar * 64 + ah * 16 + ag * 2 + 1] = pack2(acc.z, acc.w);
    }
    __syncthreads();

    // ---- phase 2: C = A + head_out @ o_w + o_b (full K, dot2) ------------
    {
        const int c = tid & 127, rh = tid >> 7;
        const unsigned* oH = wH + OFF_O;
        float acc[4];
#pragma unroll
        for (int r = 0; r < 4; ++r) acc[r] = 0.f;
        for (int kp4 = 0; kp4 < 16; ++kp4) {
            unsigned w0 = oH[(kp4 * 4 + 0) * 128 + c];
            unsigned w1 = oH[(kp4 * 4 + 1) * 128 + c];
            unsigned w2 = oH[(kp4 * 4 + 2) * 128 + c];
            unsigned w3 = oH[(kp4 * 4 + 3) * 128 + c];
#pragma unroll
            for (int r = 0; r < 4; ++r) {
                uint4 t = *(const uint4*)(&BtH[(rh * 4 + r) * 64 + kp4 * 4]);
                acc[r] = dot2(t.x, w0, acc[r]); acc[r] = dot2(t.y, w1, acc[r]);
                acc[r] = dot2(t.z, w2, acc[r]); acc[r] = dot2(t.w, w3, acc[r]);
            }
        }
        const float ob = o_b[c];
#pragma unroll
        for (int r = 0; r < 4; ++r) {
            const int rr = rh * 4 + r;
            C[rr * 128 + c] = A[rr * 128 + c] + ob + acc[r];
        }
    }
    __syncthreads();
    ln_rows8_pack(C, CH, n1_g, n1_b, tid);   // C = tgt (f32 + packed)
    __syncthreads();

    // ---- phase 3: Hh = relu(CH @ l1_w + l1_b)  [8 x 256] f16 out ---------
    {
        const int f = tid;
        const unsigned* l1H = wH + OFF_L1;
        float acc[8];
#pragma unroll
        for (int r = 0; r < 8; ++r) acc[r] = 0.f;
        for (int kp4 = 0; kp4 < 16; ++kp4) {
            unsigned w0 = l1H[(kp4 * 4 + 0) * 256 + f];
            unsigned w1 = l1H[(kp4 * 4 + 1) * 256 + f];
            unsigned w2 = l1H[(kp4 * 4 + 2) * 256 + f];
            unsigned w3 = l1H[(kp4 * 4 + 3) * 256 + f];
#pragma unroll
            for (int r = 0; r < 8; ++r) {
                uint4 t = *(const uint4*)(&CH[r * 64 + kp4 * 4]);
                acc[r] = dot2(t.x, w0, acc[r]); acc[r] = dot2(t.y, w1, acc[r]);
                acc[r] = dot2(t.z, w2, acc[r]); acc[r] = dot2(t.w, w3, acc[r]);
            }
        }
        const float bb = l1_b[f];
#pragma unroll
        for (int r = 0; r < 8; ++r) Hh[r * 256 + f] = (_Float16)relu(acc[r] + bb);
    }
    __syncthreads();

    // ---- phase 4: C += Hh @ l2_w + l2_b (full K=256, dot2) ---------------
    {
        const int c = tid & 127, rh = tid >> 7;
        const unsigned* l2H = wH + OFF_L2;
        const unsigned* HhU = (const unsigned*)Hh;   // 8 x 128 dwords
        float acc[4];
#pragma unroll
        for (int r = 0; r < 4; ++r) acc[r] = 0.f;
        for (int kp4 = 0; kp4 < 32; ++kp4) {
            unsigned w0 = l2H[(kp4 * 4 + 0) * 128 + c];
            unsigned w1 = l2H[(kp4 * 4 + 1) * 128 + c];
            unsigned w2 = l2H[(kp4 * 4 + 2) * 128 + c];
            unsigned w3 = l2H[(kp4 * 4 + 3) * 128 + c];
#pragma unroll
            for (int r = 0; r < 4; ++r) {
                uint4 t = *(const uint4*)(&HhU[(rh * 4 + r) * 128 + kp4 * 4]);
                acc[r] = dot2(t.x, w0, acc[r]); acc[r] = dot2(t.y, w1, acc[r]);
                acc[r] = dot2(t.z, w2, acc[r]); acc[r] = dot2(t.w, w3, acc[r]);
            }
        }
        const float lb = l2_b[c];
#pragma unroll
        for (int r = 0; r < 4; ++r) {
            const int rr = rh * 4 + r;
            C[rr * 128 + c] += lb + acc[r];
        }
    }
    __syncthreads();
    ln_rows8_pack(C, CH, n3_g, n3_b, tid);   // C = final tgt (f32 + packed)
    __syncthreads();

    // ---- phase 5: fused = [F, C] @ fu_w + fu_b; BN staging in A ----------
    {
        const int c = tid & 63, rg = tid >> 6;   // 4 groups x 2 rows
        const unsigned* fuH = wH + OFF_FU;
        float acc[2];
        const float fb = fu_b[c];
#pragma unroll
        for (int r = 0; r < 2; ++r) acc[r] = fb;
        for (int kp4 = 0; kp4 < 8; ++kp4) {      // features half: kp 0..31
            unsigned w0 = fuH[(kp4 * 4 + 0) * 64 + c];
            unsigned w1 = fuH[(kp4 * 4 + 1) * 64 + c];
            unsigned w2 = fuH[(kp4 * 4 + 2) * 64 + c];
            unsigned w3 = fuH[(kp4 * 4 + 3) * 64 + c];
#pragma unroll
            for (int r = 0; r < 2; ++r) {
                uint4 t = *(const uint4*)(&FH[(rg * 2 + r) * 32 + kp4 * 4]);
                acc[r] = dot2(t.x, w0, acc[r]); acc[r] = dot2(t.y, w1, acc[r]);
                acc[r] = dot2(t.z, w2, acc[r]); acc[r] = dot2(t.w, w3, acc[r]);
            }
        }
        for (int kp4 = 0; kp4 < 16; ++kp4) {     // tgt half: kp 32..95
            unsigned w0 = fuH[(32 + kp4 * 4 + 0) * 64 + c];
            unsigned w1 = fuH[(32 + kp4 * 4 + 1) * 64 + c];
            unsigned w2 = fuH[(32 + kp4 * 4 + 2) * 64 + c];
            unsigned w3 = fuH[(32 + kp4 * 4 + 3) * 64 + c];
#pragma unroll
            for (int r = 0; r < 2; ++r) {
                uint4 t = *(const uint4*)(&CH[(rg * 2 + r) * 64 + kp4 * 4]);
                acc[r] = dot2(t.x, w0, acc[r]); acc[r] = dot2(t.y, w1, acc[r]);
                acc[r] = dot2(t.z, w2, acc[r]); acc[r] = dot2(t.w, w3, acc[r]);
            }
        }
#pragma unroll
        for (int r = 0; r < 2; ++r) {
            int row = rg * 2 + r;
            float v = acc[r];
            fused[(r0 + row) * 64 + c] = v;
            A[row * 64 + c] = v;
        }
    }
    __syncthreads();
    if (tid < 64) {
        float s = 0.f, s2 = 0.f;
#pragma unroll
        for (int r = 0; r < 8; ++r) { float x = A[r * 64 + tid]; s += x; s2 += x * x; }
        atomicAdd(&bnSum[tid], s);
        atomicAdd(&bnSq[tid], s2);
    }
}

// ---------------------------------------------------------------------------
// K5: batchnorm (train-mode stats) + relu -> fp32 out
// ---------------------------------------------------------------------------
__global__ __launch_bounds__(256) void k5_bn_cst(
    const float* __restrict__ fused, const float* __restrict__ bnSum,
    const float* __restrict__ bnSq,
    const float* __restrict__ g, const float* __restrict__ b,
    float* __restrict__ out, int N)
{
    const int total = N * 64;
    const float invN = 1.f / (float)N;
    for (int i = blockIdx.x * 256 + threadIdx.x; i < total; i += gridDim.x * 256) {
        int c = i & 63;
        float mu = bnSum[c] * invN;
        float var = bnSq[c] * invN - mu * mu;
        float x = fused[i];
        float y = (x - mu) * rsqrtf(var + 1e-3f) * g[c] + b[c];
        out[i] = relu(y);
    }
}

// ---------------------------------------------------------------------------
extern "C" void kernel_launch(void* const* d_in, const int* in_sizes, int n_in,
                              void* d_out, int out_size, void* d_ws, size_t ws_size,
                              hipStream_t stream)
{
    const float* features = (const float*)d_in[0];
    const int*   coords   = (const int*)d_in[1];
    const float* pe_w1 = (const float*)d_in[2];
    const float* pe_b1 = (const float*)d_in[3];
    const float* pe_w2 = (const float*)d_in[4];
    const float* pe_b2 = (const float*)d_in[5];
    const float* in_w  = (const float*)d_in[6];
    const float* in_b  = (const float*)d_in[7];
    const float* q_w   = (const float*)d_in[8];
    const float* q_b   = (const float*)d_in[9];
    const float* k_w   = (const float*)d_in[10];
    const float* k_b   = (const float*)d_in[11];
    const float* v_w   = (const float*)d_in[12];
    const float* v_b   = (const float*)d_in[13];
    const float* o_w   = (const float*)d_in[14];
    const float* o_b   = (const float*)d_in[15];
    const float* n1_g  = (const float*)d_in[16];
    const float* n1_b  = (const float*)d_in[17];
    const float* l1_w  = (const float*)d_in[18];
    const float* l1_b  = (const float*)d_in[19];
    const float* l2_w  = (const float*)d_in[20];
    const float* l2_b  = (const float*)d_in[21];
    const float* n3_g  = (const float*)d_in[22];
    const float* n3_b  = (const float*)d_in[23];
    const float* fu_w  = (const float*)d_in[24];
    const float* fu_b  = (const float*)d_in[25];
    const float* bn_g  = (const float*)d_in[26];
    const float* bn_b  = (const float*)d_in[27];

    const int N = in_sizes[0] / 64;   // 8192

    float* src   = (float*)d_ws;            // N*128
    float* qs    = src + (size_t)N * 128;   // N*128
    float* ks    = qs  + (size_t)N * 128;   // N*128
    float* vs    = ks  + (size_t)N * 128;   // N*128
    float* fused = vs  + (size_t)N * 128;   // N*64
    int*   nbr    = (int*)(fused + (size_t)N * 64);   // N*16 ints
    float* bnSum  = (float*)(nbr + (size_t)N * 16);   // 64
    float* bnSq   = bnSum + 64;                       // 64 (contiguous 128)
    unsigned* wH  = (unsigned*)(bnSq + 64);           // packed weights (~320 KB)

    k0_pack<<<64, 256, 0, stream>>>(q_w, k_w, v_w, o_w, l1_w, l2_w,
                                    in_w, pe_w2, fu_w, wH);
    ka_pre_cst<<<N / 8 + N / 16, 256, 0, stream>>>(features, coords,
                                                   pe_w1, pe_b1, pe_b2, in_b,
                                                   wH,
                                                   src, qs, ks, vs, nbr, bnSum, N);
    k4_main_cst<<<N / 8, 256, 0, stream>>>(features, src, qs, ks, vs, nbr,
                                           q_b, k_b, v_b, wH, o_b, n1_g, n1_b,
                                           l1_b, l2_b, n3_g, n3_b,
                                           fu_b, fused, bnSum, bnSq);
    k5_bn_cst<<<512, 256, 0, stream>>>(fused, bnSum, bnSq, bn_g, bn_b,
                                       (float*)d_out, N);
}